// Round 6
// baseline (329.910 us; speedup 1.0000x reference)
//
#include <hip/hip_runtime.h>
#include <hip/hip_bf16.h>

// Self-attention fwd, all-FP16 MFMA pipeline.
// 256x256-tile 8-wave GEMM with HK-style phased schedule: 2 phases per
// BK=32 K-tile (16 MFMA each), double-buffered 64KB LDS, per-phase
// half-tile global_load_lds staging, counted vmcnt(2) (never 0 mid-loop),
// setprio around MFMA, slot-rotation LDS swizzle (both-sides).

typedef __attribute__((ext_vector_type(8))) _Float16 f16x8;
typedef __attribute__((ext_vector_type(4))) _Float16 f16x4;
typedef __attribute__((ext_vector_type(4))) float f32x4;

static __device__ __forceinline__ void gl_lds16(const void* g, void* s) {
  __builtin_amdgcn_global_load_lds(
      (const __attribute__((address_space(1))) void*)g,
      (__attribute__((address_space(3))) void*)s, 16, 0, 0);
}

// ---------------- fp32 -> fp16 convert ----------------
__global__ __launch_bounds__(256) void cvt16(
    const float* __restrict__ x, _Float16* __restrict__ o, int n4) {
  int i = blockIdx.x * 256 + threadIdx.x;
  if (i >= n4) return;
  float4 v = reinterpret_cast<const float4*>(x)[i];
  f16x4 r = {(_Float16)v.x, (_Float16)v.y, (_Float16)v.z, (_Float16)v.w};
  reinterpret_cast<f16x4*>(o)[i] = r;
}

// ---------------- bias pack (bq|bk|bv) ----------------
__global__ __launch_bounds__(256) void pack_bias(
    const float* __restrict__ bq, const float* __restrict__ bk,
    const float* __restrict__ bv, float* __restrict__ o) {
  int i = blockIdx.x * 256 + threadIdx.x;
  if (i >= 3072) return;
  o[i] = (i < 1024) ? bq[i] : (i < 2048) ? bk[i - 1024] : bv[i - 2048];
}

// ---------------- 256x256 phased GEMM: C = alpha * A @ B^T (+bias) ------
// A: [M][K] fp16 row-major, B: [N][K] fp16 row-major.
// EPI 0: fp32 Cf[bz*sC + row*N + col].  EPI 1: fp16 Ch[row*N+col] (flat).
// EPI 3: fused QKV routing (col<1024 Q, <2048 K, else V^T [b][d][s], S=2048).
// BB: B batch selected by row-block (row0>>11) instead of blockIdx.z.
template <int EPI, bool BB>
__global__ __launch_bounds__(512, 2) void gemm256(
    const _Float16* __restrict__ A, const _Float16* __restrict__ B,
    const float* __restrict__ bias, float* __restrict__ Cf,
    _Float16* __restrict__ Ch, _Float16* __restrict__ C2,
    _Float16* __restrict__ C3,
    int M, int N, int K, long sA, long sB, long sC, float alpha) {
  // [dbuf][A|B][half][128 rows x 32 cols] fp16 = 64 KiB total
  __shared__ _Float16 lds[2][2][2][4096];

  const int tid = threadIdx.x;
  const int w = tid >> 6;            // 0..7
  const int lane = tid & 63;
  const int wr = w >> 2;             // 0..1  (M half)
  const int wc = w & 3;              // 0..3  (N quarter)
  const int lr = lane & 15;
  const int q = lane >> 4;
  const long bz = blockIdx.z;
  const long row0 = (long)blockIdx.y * 256;
  const long col0 = (long)blockIdx.x * 256;
  const int nt = K >> 5;

  const _Float16* pA = A + bz * sA;
  const _Float16* pB = BB ? (B + (row0 >> 11) * sB) : (B + bz * sB);

  f32x4 acc[8][4] = {};

  // staging: thread covers physical 16B slot sp of a [128][32] half-tile.
  // swizzle: logical (r,c4) lives at physical slot r*4 + ((r+c4)&3).
  const int sp = (w << 6) | lane;        // 0..511
  const int sr = sp >> 2;                // row 0..127
  const int sc = ((sp & 3) - sr) & 3;    // logical c4 for this slot

  auto stage = [&](int tt, int ab, int half) {
    if (tt >= nt) return;
    const long gr = (ab ? col0 : row0) + half * 128 + sr;
    const _Float16* src = (ab ? pB : pA) + gr * (long)K + (long)tt * 32 + sc * 8;
    gl_lds16(src, (void*)&lds[tt & 1][ab][half][w << 9]);
  };
  auto rdA = [&](int d, int rbase) -> f16x8 {
    const int r = rbase + lr;
    const int s = (r << 2) | ((r + q) & 3);
    return *(const f16x8*)&lds[d][0][wr][s << 3];
  };
  auto rdB = [&](int d, int n) -> f16x8 {
    const int r = ((wc & 1) << 6) + n * 16 + lr;
    const int s = (r << 2) | ((r + q) & 3);
    return *(const f16x8*)&lds[d][1][wc >> 1][s << 3];
  };

  // prologue: tile0 fully + tile1's B halves; vmcnt(2) keeps tile1-B in flight
  stage(0, 0, 0); stage(0, 0, 1); stage(0, 1, 0); stage(0, 1, 1);
  stage(1, 1, 0); stage(1, 1, 1);
  if (nt > 1) asm volatile("s_waitcnt vmcnt(2)" ::: "memory");
  else        asm volatile("s_waitcnt vmcnt(0)" ::: "memory");
  __builtin_amdgcn_s_barrier();
  __builtin_amdgcn_sched_barrier(0);

  f16x8 aa[4], bb[4];
  for (int t = 0; t < nt; ++t) {
    const int d = t & 1;
    // ---- phase 1: read A m0-3 + B n0-3; stage (t+1) A-halves ----
#pragma unroll
    for (int m = 0; m < 4; ++m) aa[m] = rdA(d, m * 16);
#pragma unroll
    for (int n = 0; n < 4; ++n) bb[n] = rdB(d, n);
    stage(t + 1, 0, 0); stage(t + 1, 0, 1);
    __builtin_amdgcn_s_barrier();
    asm volatile("s_waitcnt lgkmcnt(0)" ::: "memory");
    __builtin_amdgcn_sched_barrier(0);
    __builtin_amdgcn_s_setprio(1);
#pragma unroll
    for (int m = 0; m < 4; ++m)
#pragma unroll
      for (int n = 0; n < 4; ++n)
        acc[m][n] = __builtin_amdgcn_mfma_f32_16x16x32_f16(aa[m], bb[n], acc[m][n], 0, 0, 0);
    __builtin_amdgcn_s_setprio(0);
    __builtin_amdgcn_sched_barrier(0);
    __builtin_amdgcn_s_barrier();
    // ---- phase 2: read A m4-7 (B stays in regs); stage (t+2) B-halves ----
#pragma unroll
    for (int m = 0; m < 4; ++m) aa[m] = rdA(d, 64 + m * 16);
    stage(t + 2, 1, 0); stage(t + 2, 1, 1);
    __builtin_amdgcn_s_barrier();
    asm volatile("s_waitcnt lgkmcnt(0)" ::: "memory");
    __builtin_amdgcn_sched_barrier(0);
    __builtin_amdgcn_s_setprio(1);
#pragma unroll
    for (int m = 0; m < 4; ++m)
#pragma unroll
      for (int n = 0; n < 4; ++n)
        acc[4 + m][n] = __builtin_amdgcn_mfma_f32_16x16x32_f16(aa[m], bb[n], acc[4 + m][n], 0, 0, 0);
    __builtin_amdgcn_s_setprio(0);
    __builtin_amdgcn_sched_barrier(0);
    // counted drain: land tile t+1 fully, keep tile t+2's B in flight
    if (t + 2 < nt) asm volatile("s_waitcnt vmcnt(2)" ::: "memory");
    else            asm volatile("s_waitcnt vmcnt(0)" ::: "memory");
    __builtin_amdgcn_s_barrier();
    __builtin_amdgcn_sched_barrier(0);
  }

  // ---- epilogue ----
#pragma unroll
  for (int m = 0; m < 8; ++m)
#pragma unroll
    for (int n = 0; n < 4; ++n)
#pragma unroll
      for (int r = 0; r < 4; ++r) {
        const long row = row0 + wr * 128 + m * 16 + q * 4 + r;
        const long col = col0 + wc * 64 + n * 16 + lr;
        float v = acc[m][n][r] * alpha;
        if (bias) v += bias[col];
        if (EPI == 0) {
          Cf[bz * sC + row * (long)N + col] = v;
        } else if (EPI == 1) {
          Ch[row * (long)N + col] = (_Float16)v;
        } else {  // EPI 3: fused QKV routing, S=2048
          if (col < 1024) {
            Ch[row * 1024 + col] = (_Float16)v;
          } else if (col < 2048) {
            C2[row * 1024 + (col - 1024)] = (_Float16)v;
          } else {
            const long b2 = row >> 11;
            const long s2 = row & 2047;
            C3[(b2 * 1024 + (col - 2048)) * 2048 + s2] = (_Float16)v;
          }
        }
      }
}

// ---------------- row softmax (in-place fp32) + fp16 copy ----------------
__global__ __launch_bounds__(256) void softmax_rows(
    float* __restrict__ Sc, _Float16* __restrict__ P) {
  const long row = blockIdx.x;
  float* p = Sc + row * 2048;
  const int tid = threadIdx.x;
  float4 a = reinterpret_cast<float4*>(p)[tid * 2];
  float4 b = reinterpret_cast<float4*>(p)[tid * 2 + 1];
  float x[8] = {a.x, a.y, a.z, a.w, b.x, b.y, b.z, b.w};
  float m = x[0];
#pragma unroll
  for (int j = 1; j < 8; ++j) m = fmaxf(m, x[j]);
#pragma unroll
  for (int o = 32; o >= 1; o >>= 1) m = fmaxf(m, __shfl_xor(m, o));
  __shared__ float red[4], red2[4];
  if ((tid & 63) == 0) red[tid >> 6] = m;
  __syncthreads();
  m = fmaxf(fmaxf(red[0], red[1]), fmaxf(red[2], red[3]));
  float s = 0.f;
#pragma unroll
  for (int j = 0; j < 8; ++j) { x[j] = expf(x[j] - m); s += x[j]; }
#pragma unroll
  for (int o = 32; o >= 1; o >>= 1) s += __shfl_xor(s, o);
  if ((tid & 63) == 0) red2[tid >> 6] = s;
  __syncthreads();
  s = red2[0] + red2[1] + red2[2] + red2[3];
  const float inv = 1.0f / s;
#pragma unroll
  for (int j = 0; j < 8; ++j) x[j] *= inv;
  reinterpret_cast<float4*>(p)[tid * 2] = make_float4(x[0], x[1], x[2], x[3]);
  reinterpret_cast<float4*>(p)[tid * 2 + 1] = make_float4(x[4], x[5], x[6], x[7]);
  _Float16* qp = P + row * 2048;
  reinterpret_cast<f16x4*>(qp)[tid * 2] =
      (f16x4){(_Float16)x[0], (_Float16)x[1], (_Float16)x[2], (_Float16)x[3]};
  reinterpret_cast<f16x4*>(qp)[tid * 2 + 1] =
      (f16x4){(_Float16)x[4], (_Float16)x[5], (_Float16)x[6], (_Float16)x[7]};
}

extern "C" void kernel_launch(void* const* d_in, const int* in_sizes, int n_in,
                              void* d_out, int out_size, void* d_ws, size_t ws_size,
                              hipStream_t stream) {
  const float* x  = (const float*)d_in[0];
  const float* Wk = (const float*)d_in[1];
  const float* bk = (const float*)d_in[2];
  const float* Wq = (const float*)d_in[3];
  const float* bq = (const float*)d_in[4];
  const float* Wv = (const float*)d_in[5];
  const float* bv = (const float*)d_in[6];
  const float* Wo = (const float*)d_in[7];
  const float* bo = (const float*)d_in[8];

  float* out  = (float*)d_out;                  // [4,2048,1024]
  float* attn = (float*)d_out + 8388608;        // [4,2048,2048]

  const size_t MB = 1024 * 1024;
  unsigned char* ws = (unsigned char*)d_ws;
  _Float16* xh   = (_Float16*)(ws + 0 * MB);    // [8192][1024]       16 MB
  _Float16* Wf   = (_Float16*)(ws + 16 * MB);   // [3072][1024] q|k|v  6 MB
  _Float16* Woh  = (_Float16*)(ws + 22 * MB);   //                     2 MB
  float*    bqkv = (float*)   (ws + 24 * MB);   // [3072]
  _Float16* Qh   = (_Float16*)(ws + 25 * MB);   // [4][2048][1024]    16 MB
  _Float16* Kh   = (_Float16*)(ws + 41 * MB);   //                    16 MB
  _Float16* Vt   = (_Float16*)(ws + 57 * MB);   // [4][1024][2048]    16 MB
  _Float16* Ph   = (_Float16*)(ws + 73 * MB);   // [4][2048][2048]    32 MB
  _Float16* ath  = (_Float16*)(ws + 105 * MB);  // [4][2048][1024]    16 MB

  dim3 blk(256);
  dim3 blk5(512);

  hipLaunchKernelGGL(cvt16, dim3(8192), blk, 0, stream, x, xh, 2097152);
  hipLaunchKernelGGL(cvt16, dim3(1024), blk, 0, stream, Wq, Wf, 262144);
  hipLaunchKernelGGL(cvt16, dim3(1024), blk, 0, stream, Wk, Wf + 1048576, 262144);
  hipLaunchKernelGGL(cvt16, dim3(1024), blk, 0, stream, Wv, Wf + 2097152, 262144);
  hipLaunchKernelGGL(cvt16, dim3(1024), blk, 0, stream, Wo, Woh, 262144);
  hipLaunchKernelGGL(pack_bias, dim3(12), blk, 0, stream, bq, bk, bv, bqkv);

  // fused QKV: [Q|K|V] = x@[Wq|Wk|Wv]^T + b  (V written transposed per batch)
  hipLaunchKernelGGL((gemm256<3, false>), dim3(12, 32, 1), blk5, 0, stream,
                     xh, Wf, bqkv, (float*)nullptr, Qh, Kh, Vt,
                     8192, 3072, 1024, 0L, 0L, 0L, 1.0f);
  // scores = scale * Q@K^T  (batched by z, fp32 into d_out attention region)
  hipLaunchKernelGGL((gemm256<0, false>), dim3(8, 8, 4), blk5, 0, stream,
                     Qh, Kh, (const float*)nullptr, attn,
                     (_Float16*)nullptr, (_Float16*)nullptr, (_Float16*)nullptr,
                     2048, 2048, 1024, 2097152L, 2097152L, 4194304L, 0.03125f);
  // softmax rows (in-place fp32) + fp16 P
  hipLaunchKernelGGL(softmax_rows, dim3(8192), blk, 0, stream, attn, Ph);
  // att_out = P @ V   (M flattened to 8192; V batch = row block >> 11)
  hipLaunchKernelGGL((gemm256<1, true>), dim3(4, 32, 1), blk5, 0, stream,
                     Ph, Vt, (const float*)nullptr, (float*)nullptr, ath,
                     (_Float16*)nullptr, (_Float16*)nullptr,
                     8192, 1024, 2048, 0L, 2097152L, 0L, 1.0f);
  // out = att_out@Wo^T + bo  (fp32 into d_out)
  hipLaunchKernelGGL((gemm256<0, false>), dim3(4, 32, 1), blk5, 0, stream,
                     ath, Woh, bo, out,
                     (_Float16*)nullptr, (_Float16*)nullptr, (_Float16*)nullptr,
                     8192, 1024, 1024, 0L, 0L, 0L, 1.0f);
}

// Round 7
// 306.744 us; speedup vs baseline: 1.0755x; 1.0755x over previous
//
#include <hip/hip_runtime.h>
#include <hip/hip_bf16.h>

// Self-attention fwd, all-FP16 MFMA pipeline.
// gemm256: 256x256 tile, 8 waves, BK=32, TRIPLE-buffered LDS (96KB),
//   2 phases/K-tile (16 MFMA each), stage tile kt+2 during kt (3-4 phase lead),
//   counted vmcnt(4) at K-tile end, full-rotation swizzle (2-way = free).
// gemm128: R5-proven 128x128 loop with the same swizzle fix (PV, O-proj).

typedef __attribute__((ext_vector_type(8))) _Float16 f16x8;
typedef __attribute__((ext_vector_type(4))) _Float16 f16x4;
typedef __attribute__((ext_vector_type(4))) float f32x4;

static __device__ __forceinline__ void gl_lds16(const void* g, void* s) {
  __builtin_amdgcn_global_load_lds(
      (const __attribute__((address_space(1))) void*)g,
      (__attribute__((address_space(3))) void*)s, 16, 0, 0);
}

// ---------------- fp32 -> fp16 convert ----------------
__global__ __launch_bounds__(256) void cvt16(
    const float* __restrict__ x, _Float16* __restrict__ o, int n4) {
  int i = blockIdx.x * 256 + threadIdx.x;
  if (i >= n4) return;
  float4 v = reinterpret_cast<const float4*>(x)[i];
  f16x4 r = {(_Float16)v.x, (_Float16)v.y, (_Float16)v.z, (_Float16)v.w};
  reinterpret_cast<f16x4*>(o)[i] = r;
}

// ---------------- bias pack (bq|bk|bv) ----------------
__global__ __launch_bounds__(256) void pack_bias(
    const float* __restrict__ bq, const float* __restrict__ bk,
    const float* __restrict__ bv, float* __restrict__ o) {
  int i = blockIdx.x * 256 + threadIdx.x;
  if (i >= 3072) return;
  o[i] = (i < 1024) ? bq[i] : (i < 2048) ? bk[i - 1024] : bv[i - 2048];
}

// ======================= 256x256 phased GEMM =======================
// C = alpha * A @ B^T (+bias).  A:[M][K], B:[N][K] fp16 row-major.
// EPI 0: fp32 Cf.  EPI 3: fused QKV routing (Q | K | V^T per batch, S=2048).
template <int EPI>
__global__ __launch_bounds__(512, 2) void gemm256(
    const _Float16* __restrict__ A, const _Float16* __restrict__ B,
    const float* __restrict__ bias, float* __restrict__ Cf,
    _Float16* __restrict__ Ch, _Float16* __restrict__ C2,
    _Float16* __restrict__ C3,
    int M, int N, int K, long sA, long sB, long sC, float alpha) {
  __shared__ _Float16 lds[3][2][8192];  // [buf][A|B][256 rows * 32 cols], swizzled

  const int tid = threadIdx.x;
  const int w = tid >> 6, lane = tid & 63;
  const int wr = w >> 2, wc = w & 3;      // 2M x 4N waves
  const int lr = lane & 15, q = lane >> 4;
  const long bz = blockIdx.z;
  const long row0 = (long)blockIdx.y * 256;
  const long col0 = (long)blockIdx.x * 256;
  const int nt = K >> 5;

  const _Float16* pA = A + bz * sA;
  const _Float16* pB = B + bz * sB;

  f32x4 acc[8][4] = {};

  // staging: physical 16B slot s in [0,1024); thread covers s=tid, tid+512.
  // physical slot for logical (r,c): 4r + ((c + (r>>1)) & 3)  -> 2-way banks.
  const int r0 = tid >> 2, c0 = ((tid & 3) - (r0 >> 1)) & 3;
  const int s1 = tid + 512;
  const int r1 = s1 >> 2, c1 = ((s1 & 3) - (r1 >> 1)) & 3;

  auto stage = [&](int kt, int ab) {
    if (kt >= nt) return;
    const int bf = kt % 3;
    const _Float16* src = ab ? pB : pA;
    const long base = ab ? col0 : row0;
    const long gk = (long)kt * 32;
    gl_lds16(src + (base + r0) * (long)K + gk + c0 * 8, &lds[bf][ab][w << 9]);
    gl_lds16(src + (base + r1) * (long)K + gk + c1 * 8, &lds[bf][ab][4096 + (w << 9)]);
  };
  auto rd = [&](int bf, int ab, int r) -> f16x8 {
    const int slot = (r << 2) + ((q + (r >> 1)) & 3);
    return *(const f16x8*)&lds[bf][ab][slot << 3];
  };

  // prologue: tiles 0,1 staged (8 ops); vmcnt(4) -> tile 0 landed
  stage(0, 0); stage(0, 1); stage(1, 0); stage(1, 1);
  asm volatile("s_waitcnt vmcnt(4)" ::: "memory");
  __builtin_amdgcn_s_barrier();
  __builtin_amdgcn_sched_barrier(0);

  f16x8 a[4], b[4];
  for (int kt = 0; kt < nt; ++kt) {
    const int bf = kt % 3;
    // ---- phase 1: A rows 0-63 of wave half + all B; stage (kt+2) A ----
#pragma unroll
    for (int m = 0; m < 4; ++m) a[m] = rd(bf, 0, wr * 128 + m * 16 + lr);
#pragma unroll
    for (int n = 0; n < 4; ++n) b[n] = rd(bf, 1, wc * 64 + n * 16 + lr);
    stage(kt + 2, 0);
    __builtin_amdgcn_s_barrier();
    asm volatile("s_waitcnt lgkmcnt(0)" ::: "memory");
    __builtin_amdgcn_sched_barrier(0);
    __builtin_amdgcn_s_setprio(1);
#pragma unroll
    for (int m = 0; m < 4; ++m)
#pragma unroll
      for (int n = 0; n < 4; ++n)
        acc[m][n] = __builtin_amdgcn_mfma_f32_16x16x32_f16(a[m], b[n], acc[m][n], 0, 0, 0);
    __builtin_amdgcn_s_setprio(0);
    __builtin_amdgcn_sched_barrier(0);
    __builtin_amdgcn_s_barrier();
    // ---- phase 2: A rows 64-127 (B retained in regs); stage (kt+2) B ----
#pragma unroll
    for (int m = 0; m < 4; ++m) a[m] = rd(bf, 0, wr * 128 + 64 + m * 16 + lr);
    stage(kt + 2, 1);
    __builtin_amdgcn_s_barrier();
    asm volatile("s_waitcnt lgkmcnt(0)" ::: "memory");
    __builtin_amdgcn_sched_barrier(0);
    __builtin_amdgcn_s_setprio(1);
#pragma unroll
    for (int m = 0; m < 4; ++m)
#pragma unroll
      for (int n = 0; n < 4; ++n)
        acc[4 + m][n] = __builtin_amdgcn_mfma_f32_16x16x32_f16(a[m], b[n], acc[4 + m][n], 0, 0, 0);
    __builtin_amdgcn_s_setprio(0);
    __builtin_amdgcn_sched_barrier(0);
    // counted drain: tile kt+1 must be landed; kt+2 stays in flight
    if (kt < nt - 2) asm volatile("s_waitcnt vmcnt(4)" ::: "memory");
    else             asm volatile("s_waitcnt vmcnt(0)" ::: "memory");
    __builtin_amdgcn_s_barrier();
    __builtin_amdgcn_sched_barrier(0);
  }

#pragma unroll
  for (int m = 0; m < 8; ++m)
#pragma unroll
    for (int n = 0; n < 4; ++n)
#pragma unroll
      for (int r = 0; r < 4; ++r) {
        const long row = row0 + wr * 128 + m * 16 + q * 4 + r;
        const long col = col0 + wc * 64 + n * 16 + lr;
        float v = acc[m][n][r] * alpha;
        if (bias) v += bias[col];
        if (EPI == 0) {
          Cf[bz * sC + row * (long)N + col] = v;
        } else {  // EPI 3: fused QKV routing, S=2048
          if (col < 1024) {
            Ch[row * 1024 + col] = (_Float16)v;
          } else if (col < 2048) {
            C2[row * 1024 + (col - 1024)] = (_Float16)v;
          } else {
            const long b2 = row >> 11;
            const long s2 = row & 2047;
            C3[(b2 * 1024 + (col - 2048)) * 2048 + s2] = (_Float16)v;
          }
        }
      }
}

// ======================= 128x128 GEMM (R5-proven loop) =======================
// EPI 0: fp32 Cf (+bias).  EPI 1: fp16 flat Ch.
// BB: B batch selected by row block (row0>>11)  [for PV].
template <int EPI, bool BB>
__global__ __launch_bounds__(256) void gemm128(
    const _Float16* __restrict__ A, const _Float16* __restrict__ B,
    const float* __restrict__ bias, float* __restrict__ Cf,
    _Float16* __restrict__ Ch,
    int M, int N, int K, long sA, long sB, long sC, float alpha) {
  __shared__ _Float16 lds[3][2][4096];  // [buf][A|B][128 rows * 32 cols], swizzled

  const int tid = threadIdx.x;
  const int w = tid >> 6, lane = tid & 63;
  const int wr = w >> 1, wc = w & 1;
  const int lr = lane & 15, q = lane >> 4;
  const long bz = blockIdx.z;
  const long row0 = (long)blockIdx.y * 128;
  const long col0 = (long)blockIdx.x * 128;
  const int nt = K >> 5;

  const _Float16* pA = A + bz * sA;
  const _Float16* pB = BB ? (B + (row0 >> 11) * sB) : (B + bz * sB);

  f32x4 acc[4][4] = {};

  const int r0 = tid >> 2, c0 = ((tid & 3) - (r0 >> 1)) & 3;
  const int s1 = tid + 256;
  const int r1 = s1 >> 2, c1 = ((s1 & 3) - (r1 >> 1)) & 3;

  auto stage = [&](int kt) {
    if (kt >= nt) return;
    const int bf = kt % 3;
    const long gk = (long)kt * 32;
#pragma unroll
    for (int ab = 0; ab < 2; ++ab) {
      const _Float16* src = ab ? pB : pA;
      const long base = ab ? col0 : row0;
      gl_lds16(src + (base + r0) * (long)K + gk + c0 * 8, &lds[bf][ab][w << 9]);
      gl_lds16(src + (base + r1) * (long)K + gk + c1 * 8, &lds[bf][ab][2048 + (w << 9)]);
    }
  };
  auto rd = [&](int bf, int ab, int r) -> f16x8 {
    const int slot = (r << 2) + ((q + (r >> 1)) & 3);
    return *(const f16x8*)&lds[bf][ab][slot << 3];
  };

  stage(0); stage(1);
  asm volatile("s_waitcnt vmcnt(4)" ::: "memory");
  __builtin_amdgcn_s_barrier();
  __builtin_amdgcn_sched_barrier(0);

  for (int kt = 0; kt < nt; ++kt) {
    const int bf = kt % 3;
    stage(kt + 2);
    f16x8 a[4], b[4];
#pragma unroll
    for (int m = 0; m < 4; ++m) a[m] = rd(bf, 0, wr * 64 + m * 16 + lr);
#pragma unroll
    for (int n = 0; n < 4; ++n) b[n] = rd(bf, 1, wc * 64 + n * 16 + lr);
#pragma unroll
    for (int m = 0; m < 4; ++m)
#pragma unroll
      for (int n = 0; n < 4; ++n)
        acc[m][n] = __builtin_amdgcn_mfma_f32_16x16x32_f16(a[m], b[n], acc[m][n], 0, 0, 0);
    if (kt < nt - 2) asm volatile("s_waitcnt vmcnt(4)" ::: "memory");
    else             asm volatile("s_waitcnt vmcnt(0)" ::: "memory");
    __builtin_amdgcn_s_barrier();
    __builtin_amdgcn_sched_barrier(0);
  }

#pragma unroll
  for (int m = 0; m < 4; ++m)
#pragma unroll
    for (int n = 0; n < 4; ++n)
#pragma unroll
      for (int r = 0; r < 4; ++r) {
        const long row = row0 + wr * 64 + m * 16 + q * 4 + r;
        const long col = col0 + wc * 64 + n * 16 + lr;
        float v = acc[m][n][r] * alpha;
        if (bias) v += bias[col];
        if (EPI == 0) Cf[bz * sC + row * (long)N + col] = v;
        else          Ch[row * (long)N + col] = (_Float16)v;
      }
}

// ---------------- row softmax (in-place fp32) + fp16 copy ----------------
__global__ __launch_bounds__(256) void softmax_rows(
    float* __restrict__ Sc, _Float16* __restrict__ P) {
  const long row = blockIdx.x;
  float* p = Sc + row * 2048;
  const int tid = threadIdx.x;
  float4 a = reinterpret_cast<float4*>(p)[tid * 2];
  float4 b = reinterpret_cast<float4*>(p)[tid * 2 + 1];
  float x[8] = {a.x, a.y, a.z, a.w, b.x, b.y, b.z, b.w};
  float m = x[0];
#pragma unroll
  for (int j = 1; j < 8; ++j) m = fmaxf(m, x[j]);
#pragma unroll
  for (int o = 32; o >= 1; o >>= 1) m = fmaxf(m, __shfl_xor(m, o));
  __shared__ float red[4], red2[4];
  if ((tid & 63) == 0) red[tid >> 6] = m;
  __syncthreads();
  m = fmaxf(fmaxf(red[0], red[1]), fmaxf(red[2], red[3]));
  float s = 0.f;
#pragma unroll
  for (int j = 0; j < 8; ++j) { x[j] = expf(x[j] - m); s += x[j]; }
#pragma unroll
  for (int o = 32; o >= 1; o >>= 1) s += __shfl_xor(s, o);
  if ((tid & 63) == 0) red2[tid >> 6] = s;
  __syncthreads();
  s = red2[0] + red2[1] + red2[2] + red2[3];
  const float inv = 1.0f / s;
#pragma unroll
  for (int j = 0; j < 8; ++j) x[j] *= inv;
  reinterpret_cast<float4*>(p)[tid * 2] = make_float4(x[0], x[1], x[2], x[3]);
  reinterpret_cast<float4*>(p)[tid * 2 + 1] = make_float4(x[4], x[5], x[6], x[7]);
  _Float16* qp = P + row * 2048;
  reinterpret_cast<f16x4*>(qp)[tid * 2] =
      (f16x4){(_Float16)x[0], (_Float16)x[1], (_Float16)x[2], (_Float16)x[3]};
  reinterpret_cast<f16x4*>(qp)[tid * 2 + 1] =
      (f16x4){(_Float16)x[4], (_Float16)x[5], (_Float16)x[6], (_Float16)x[7]};
}

extern "C" void kernel_launch(void* const* d_in, const int* in_sizes, int n_in,
                              void* d_out, int out_size, void* d_ws, size_t ws_size,
                              hipStream_t stream) {
  const float* x  = (const float*)d_in[0];
  const float* Wk = (const float*)d_in[1];
  const float* bk = (const float*)d_in[2];
  const float* Wq = (const float*)d_in[3];
  const float* bq = (const float*)d_in[4];
  const float* Wv = (const float*)d_in[5];
  const float* bv = (const float*)d_in[6];
  const float* Wo = (const float*)d_in[7];
  const float* bo = (const float*)d_in[8];

  float* out  = (float*)d_out;                  // [4,2048,1024]
  float* attn = (float*)d_out + 8388608;        // [4,2048,2048]

  const size_t MB = 1024 * 1024;
  unsigned char* ws = (unsigned char*)d_ws;
  _Float16* xh   = (_Float16*)(ws + 0 * MB);    // [8192][1024]       16 MB
  _Float16* Wf   = (_Float16*)(ws + 16 * MB);   // [3072][1024] q|k|v  6 MB
  _Float16* Woh  = (_Float16*)(ws + 22 * MB);   //                     2 MB
  float*    bqkv = (float*)   (ws + 24 * MB);   // [3072]
  _Float16* Qh   = (_Float16*)(ws + 25 * MB);   // [4][2048][1024]    16 MB
  _Float16* Kh   = (_Float16*)(ws + 41 * MB);   //                    16 MB
  _Float16* Vt   = (_Float16*)(ws + 57 * MB);   // [4][1024][2048]    16 MB
  _Float16* Ph   = (_Float16*)(ws + 73 * MB);   // [4][2048][2048]    32 MB
  _Float16* ath  = (_Float16*)(ws + 105 * MB);  // [4][2048][1024]    16 MB

  dim3 blk(256);
  dim3 blk5(512);

  hipLaunchKernelGGL(cvt16, dim3(8192), blk, 0, stream, x, xh, 2097152);
  hipLaunchKernelGGL(cvt16, dim3(1024), blk, 0, stream, Wq, Wf, 262144);
  hipLaunchKernelGGL(cvt16, dim3(1024), blk, 0, stream, Wk, Wf + 1048576, 262144);
  hipLaunchKernelGGL(cvt16, dim3(1024), blk, 0, stream, Wv, Wf + 2097152, 262144);
  hipLaunchKernelGGL(cvt16, dim3(1024), blk, 0, stream, Wo, Woh, 262144);
  hipLaunchKernelGGL(pack_bias, dim3(12), blk, 0, stream, bq, bk, bv, bqkv);

  // fused QKV: [Q|K|V] = x@[Wq|Wk|Wv]^T + b  (V written transposed per batch)
  hipLaunchKernelGGL((gemm256<3>), dim3(12, 32, 1), blk5, 0, stream,
                     xh, Wf, bqkv, (float*)nullptr, Qh, Kh, Vt,
                     8192, 3072, 1024, 0L, 0L, 0L, 1.0f);
  // scores = scale * Q@K^T  (batched by z, fp32 into d_out attention region)
  hipLaunchKernelGGL((gemm256<0>), dim3(8, 8, 4), blk5, 0, stream,
                     Qh, Kh, (const float*)nullptr, attn,
                     (_Float16*)nullptr, (_Float16*)nullptr, (_Float16*)nullptr,
                     2048, 2048, 1024, 2097152L, 2097152L, 4194304L, 0.03125f);
  // softmax rows (in-place fp32) + fp16 P
  hipLaunchKernelGGL(softmax_rows, dim3(8192), blk, 0, stream, attn, Ph);
  // att_out = P @ V   (M flattened to 8192; V batch = row block >> 11)
  hipLaunchKernelGGL((gemm128<1, true>), dim3(8, 64, 1), blk, 0, stream,
                     Ph, Vt, (const float*)nullptr, (float*)nullptr, ath,
                     8192, 1024, 2048, 0L, 2097152L, 0L, 1.0f);
  // out = att_out@Wo^T + bo  (fp32 into d_out)
  hipLaunchKernelGGL((gemm128<0, false>), dim3(8, 64, 1), blk, 0, stream,
                     ath, Woh, bo, out, (_Float16*)nullptr,
                     8192, 1024, 1024, 0L, 0L, 0L, 1.0f);
}

// Round 8
// 257.353 us; speedup vs baseline: 1.2819x; 1.1919x over previous
//
#include <hip/hip_runtime.h>
#include <hip/hip_bf16.h>

// Self-attention fwd, fp16 MFMA pipeline with algebraic V/O fusion:
//   out = P@(x@(Wo@Wv)^T) + (Wo@bv + bo)   [valid because softmax rows sum to 1]
// GEMMs: Bvw=Wo@Wv (tiny), fused [Q|K|V'] proj, scores (fp16 out), PV -> out.
// All GEMMs: proven 128x128 triple-buffered counted-vmcnt loop, 3 blocks/CU,
// rotation LDS swizzle (bank-conflict-free, R7-verified), XCD-chunked blockIdx.

typedef __attribute__((ext_vector_type(8))) _Float16 f16x8;
typedef __attribute__((ext_vector_type(4))) _Float16 f16x4;
typedef __attribute__((ext_vector_type(4))) float f32x4;

static __device__ __forceinline__ void gl_lds16(const void* g, void* s) {
  __builtin_amdgcn_global_load_lds(
      (const __attribute__((address_space(1))) void*)g,
      (__attribute__((address_space(3))) void*)s, 16, 0, 0);
}

// ---------------- fp32 -> fp16 convert ----------------
__global__ __launch_bounds__(256) void cvt16(
    const float* __restrict__ x, _Float16* __restrict__ o, int n4) {
  int i = blockIdx.x * 256 + threadIdx.x;
  if (i >= n4) return;
  float4 v = reinterpret_cast<const float4*>(x)[i];
  f16x4 r = {(_Float16)v.x, (_Float16)v.y, (_Float16)v.z, (_Float16)v.w};
  reinterpret_cast<f16x4*>(o)[i] = r;
}

// ---------------- Wv fp32 -> WvT fp16 (transpose) ----------------
__global__ __launch_bounds__(256) void tr16(
    const float* __restrict__ Wv, _Float16* __restrict__ WvT) {
  __shared__ float t[64][65];
  const int tx = threadIdx.x & 63, ty = threadIdx.x >> 6;
  const int bx = blockIdx.x * 64, by = blockIdx.y * 64;
#pragma unroll
  for (int i = 0; i < 64; i += 4)
    t[ty + i][tx] = Wv[(long)(by + ty + i) * 1024 + bx + tx];
  __syncthreads();
#pragma unroll
  for (int i = 0; i < 64; i += 4)
    WvT[(long)(bx + ty + i) * 1024 + by + tx] = (_Float16)t[tx][ty + i];
}

// ---------------- cpb[n] = sum_d Wo[n][d]*bv[d] + bo[n] ----------------
__global__ __launch_bounds__(256) void ckern(
    const float* __restrict__ Wo, const float* __restrict__ bv,
    const float* __restrict__ bo, float* __restrict__ cpb) {
  const int n = blockIdx.x;
  const int tid = threadIdx.x;
  float s = 0.f;
  for (int d = tid; d < 1024; d += 256) s += Wo[(long)n * 1024 + d] * bv[d];
#pragma unroll
  for (int o = 32; o >= 1; o >>= 1) s += __shfl_xor(s, o);
  __shared__ float red[4];
  if ((tid & 63) == 0) red[tid >> 6] = s;
  __syncthreads();
  if (tid == 0) cpb[n] = red[0] + red[1] + red[2] + red[3] + bo[n];
}

// ---------------- bias pack (bq|bk|0) ----------------
__global__ __launch_bounds__(256) void pack_bias(
    const float* __restrict__ bq, const float* __restrict__ bk,
    float* __restrict__ o) {
  int i = blockIdx.x * 256 + threadIdx.x;
  if (i >= 3072) return;
  o[i] = (i < 1024) ? bq[i] : (i < 2048) ? bk[i - 1024] : 0.f;
}

// ======================= 128x128 GEMM =======================
// C = alpha * A @ B^T (+bias).  A:[M][K], B:[N][K] fp16 row-major.
// Triple-buffered LDS, counted vmcnt(4), rotation swizzle, XCD-chunked grid.
// EPI 0: fp32 Cf[bz*sC+row*N+col] (+bias).  EPI 1: fp16 Ch[bz*sC+row*N+col].
// EPI 3: fused QKV' routing (col<1024 Q, <2048 K, else V'^T [b][n][s], S=2048).
// BB: B batch = row0>>11 (PV).
template <int EPI, bool BB>
__global__ __launch_bounds__(256) void gemm128(
    const _Float16* __restrict__ A, const _Float16* __restrict__ B,
    const float* __restrict__ bias, float* __restrict__ Cf,
    _Float16* __restrict__ Ch, _Float16* __restrict__ C2,
    _Float16* __restrict__ C3,
    int M, int N, int K, long sA, long sB, long sC, float alpha) {
  __shared__ _Float16 lds[3][2][4096];  // [buf][A|B][128 rows * 32 cols] swizzled

  // XCD-chunked bijective remap (all grids have nwg % 8 == 0)
  const unsigned nwg = gridDim.x * gridDim.y * gridDim.z;
  unsigned flat = (blockIdx.z * gridDim.y + blockIdx.y) * gridDim.x + blockIdx.x;
  flat = (flat & 7) * (nwg >> 3) + (flat >> 3);
  const unsigned bxi = flat % gridDim.x;
  const unsigned t2 = flat / gridDim.x;
  const unsigned byi = t2 % gridDim.y;
  const long bz = t2 / gridDim.y;

  const int tid = threadIdx.x;
  const int w = tid >> 6, lane = tid & 63;
  const int wr = w >> 1, wc = w & 1;
  const int lr = lane & 15, q = lane >> 4;
  const long row0 = (long)byi * 128;
  const long col0 = (long)bxi * 128;
  const int nt = K >> 5;

  const _Float16* pA = A + bz * sA;
  const _Float16* pB = BB ? (B + (row0 >> 11) * sB) : (B + bz * sB);

  f32x4 acc[4][4] = {};

  const int r0 = tid >> 2, c0 = ((tid & 3) - (r0 >> 1)) & 3;
  const int s1 = tid + 256;
  const int r1 = s1 >> 2, c1 = ((s1 & 3) - (r1 >> 1)) & 3;

  auto stage = [&](int kt) {
    if (kt >= nt) return;
    const int bf = kt % 3;
    const long gk = (long)kt * 32;
#pragma unroll
    for (int ab = 0; ab < 2; ++ab) {
      const _Float16* src = ab ? pB : pA;
      const long base = ab ? col0 : row0;
      gl_lds16(src + (base + r0) * (long)K + gk + c0 * 8, &lds[bf][ab][w << 9]);
      gl_lds16(src + (base + r1) * (long)K + gk + c1 * 8, &lds[bf][ab][2048 + (w << 9)]);
    }
  };
  auto rd = [&](int bf, int ab, int r) -> f16x8 {
    const int slot = (r << 2) + ((q + (r >> 1)) & 3);
    return *(const f16x8*)&lds[bf][ab][slot << 3];
  };

  stage(0); stage(1);
  asm volatile("s_waitcnt vmcnt(4)" ::: "memory");
  __builtin_amdgcn_s_barrier();
  __builtin_amdgcn_sched_barrier(0);

  for (int kt = 0; kt < nt; ++kt) {
    const int bf = kt % 3;
    stage(kt + 2);
    f16x8 a[4], b[4];
#pragma unroll
    for (int m = 0; m < 4; ++m) a[m] = rd(bf, 0, wr * 64 + m * 16 + lr);
#pragma unroll
    for (int n = 0; n < 4; ++n) b[n] = rd(bf, 1, wc * 64 + n * 16 + lr);
#pragma unroll
    for (int m = 0; m < 4; ++m)
#pragma unroll
      for (int n = 0; n < 4; ++n)
        acc[m][n] = __builtin_amdgcn_mfma_f32_16x16x32_f16(a[m], b[n], acc[m][n], 0, 0, 0);
    if (kt < nt - 2) asm volatile("s_waitcnt vmcnt(4)" ::: "memory");
    else             asm volatile("s_waitcnt vmcnt(0)" ::: "memory");
    __builtin_amdgcn_s_barrier();
    __builtin_amdgcn_sched_barrier(0);
  }

#pragma unroll
  for (int m = 0; m < 4; ++m)
#pragma unroll
    for (int n = 0; n < 4; ++n)
#pragma unroll
      for (int r = 0; r < 4; ++r) {
        const long row = row0 + wr * 64 + m * 16 + q * 4 + r;
        const long col = col0 + wc * 64 + n * 16 + lr;
        float v = acc[m][n][r] * alpha;
        if (bias) v += bias[col];
        if (EPI == 0) {
          Cf[bz * sC + row * (long)N + col] = v;
        } else if (EPI == 1) {
          Ch[bz * sC + row * (long)N + col] = (_Float16)v;
        } else {  // EPI 3: fused QKV' routing, S=2048
          if (col < 1024) {
            Ch[row * 1024 + col] = (_Float16)v;
          } else if (col < 2048) {
            C2[row * 1024 + (col - 1024)] = (_Float16)v;
          } else {
            const long b2 = row >> 11;
            const long s2 = row & 2047;
            C3[(b2 * 1024 + (col - 2048)) * 2048 + s2] = (_Float16)v;
          }
        }
      }
}

// ------- row softmax: read fp16 scores, write fp32 probs + fp16 in place -------
__global__ __launch_bounds__(256) void softmax16(
    _Float16* __restrict__ Ph, float* __restrict__ attn) {
  const long row = blockIdx.x;
  _Float16* ph = Ph + row * 2048;
  float* ap = attn + row * 2048;
  const int tid = threadIdx.x;
  f16x8 v = reinterpret_cast<const f16x8*>(ph)[tid];
  float x[8];
#pragma unroll
  for (int j = 0; j < 8; ++j) x[j] = (float)v[j];
  float m = x[0];
#pragma unroll
  for (int j = 1; j < 8; ++j) m = fmaxf(m, x[j]);
#pragma unroll
  for (int o = 32; o >= 1; o >>= 1) m = fmaxf(m, __shfl_xor(m, o));
  __shared__ float red[4], red2[4];
  if ((tid & 63) == 0) red[tid >> 6] = m;
  __syncthreads();
  m = fmaxf(fmaxf(red[0], red[1]), fmaxf(red[2], red[3]));
  float s = 0.f;
#pragma unroll
  for (int j = 0; j < 8; ++j) { x[j] = expf(x[j] - m); s += x[j]; }
#pragma unroll
  for (int o = 32; o >= 1; o >>= 1) s += __shfl_xor(s, o);
  if ((tid & 63) == 0) red2[tid >> 6] = s;
  __syncthreads();
  s = red2[0] + red2[1] + red2[2] + red2[3];
  const float inv = 1.0f / s;
#pragma unroll
  for (int j = 0; j < 8; ++j) x[j] *= inv;
  reinterpret_cast<float4*>(ap)[tid * 2] = make_float4(x[0], x[1], x[2], x[3]);
  reinterpret_cast<float4*>(ap)[tid * 2 + 1] = make_float4(x[4], x[5], x[6], x[7]);
  f16x8 pv;
#pragma unroll
  for (int j = 0; j < 8; ++j) pv[j] = (_Float16)x[j];
  reinterpret_cast<f16x8*>(ph)[tid] = pv;
}

extern "C" void kernel_launch(void* const* d_in, const int* in_sizes, int n_in,
                              void* d_out, int out_size, void* d_ws, size_t ws_size,
                              hipStream_t stream) {
  const float* x  = (const float*)d_in[0];
  const float* Wk = (const float*)d_in[1];
  const float* bk = (const float*)d_in[2];
  const float* Wq = (const float*)d_in[3];
  const float* bq = (const float*)d_in[4];
  const float* Wv = (const float*)d_in[5];
  const float* bv = (const float*)d_in[6];
  const float* Wo = (const float*)d_in[7];
  const float* bo = (const float*)d_in[8];

  float* out  = (float*)d_out;                  // [4,2048,1024]
  float* attn = (float*)d_out + 8388608;        // [4,2048,2048]

  const size_t MB = 1024 * 1024;
  unsigned char* ws = (unsigned char*)d_ws;
  _Float16* xh   = (_Float16*)(ws + 0 * MB);    // [8192][1024]        16 MB
  _Float16* Wf   = (_Float16*)(ws + 16 * MB);   // [3072][1024] Wq|Wk|Bvw 6 MB
  _Float16* Woh  = (_Float16*)(ws + 22 * MB);   // Wo fp16              2 MB
  _Float16* WvT  = (_Float16*)(ws + 24 * MB);   // Wv^T fp16            2 MB
  float*    bqkv = (float*)   (ws + 26 * MB);   // [3072]
  float*    cpb  = (float*)   (ws + 26 * MB + 16384);  // [1024]
  _Float16* Qh   = (_Float16*)(ws + 27 * MB);   // [4][2048][1024]     16 MB
  _Float16* Kh   = (_Float16*)(ws + 43 * MB);   //                     16 MB
  _Float16* Vt   = (_Float16*)(ws + 59 * MB);   // V'^T [4][1024][2048] 16 MB
  _Float16* Ph   = (_Float16*)(ws + 75 * MB);   // [4][2048][2048]     32 MB

  dim3 blk(256);
  const _Float16* nullh = nullptr;

  // prep: conversions, Wv transpose, cpb, bias pack
  hipLaunchKernelGGL(cvt16, dim3(8192), blk, 0, stream, x, xh, 2097152);
  hipLaunchKernelGGL(cvt16, dim3(1024), blk, 0, stream, Wq, Wf, 262144);
  hipLaunchKernelGGL(cvt16, dim3(1024), blk, 0, stream, Wk, Wf + 1048576, 262144);
  hipLaunchKernelGGL(cvt16, dim3(1024), blk, 0, stream, Wo, Woh, 262144);
  hipLaunchKernelGGL(tr16, dim3(16, 16), blk, 0, stream, Wv, WvT);
  hipLaunchKernelGGL(ckern, dim3(1024), blk, 0, stream, Wo, bv, bo, cpb);
  hipLaunchKernelGGL(pack_bias, dim3(12), blk, 0, stream, bq, bk, bqkv);

  // Bvw[n][e] = sum_d Wo[n][d] * Wv[d][e]  ->  third slot of Wf (fp16)
  hipLaunchKernelGGL((gemm128<1, false>), dim3(8, 8, 1), blk, 0, stream,
                     Woh, WvT, (const float*)nullptr, (float*)nullptr,
                     Wf + 2097152, (_Float16*)nullh, (_Float16*)nullh,
                     1024, 1024, 1024, 0L, 0L, 0L, 1.0f);
  // fused [Q|K|V'] = x @ [Wq|Wk|Bvw]^T + [bq|bk|0]   (V' written ^T per batch)
  hipLaunchKernelGGL((gemm128<3, false>), dim3(24, 64, 1), blk, 0, stream,
                     xh, Wf, bqkv, (float*)nullptr, Qh, Kh, Vt,
                     8192, 3072, 1024, 0L, 0L, 0L, 1.0f);
  // scores (fp16) = scale * Q@K^T  (batched)
  hipLaunchKernelGGL((gemm128<1, false>), dim3(16, 16, 4), blk, 0, stream,
                     Qh, Kh, (const float*)nullptr, (float*)nullptr, Ph,
                     (_Float16*)nullh, (_Float16*)nullh,
                     2048, 2048, 1024, 2097152L, 2097152L, 4194304L, 0.03125f);
  // softmax rows: attn fp32 + Ph fp16 (in place)
  hipLaunchKernelGGL(softmax16, dim3(8192), blk, 0, stream, Ph, attn);
  // out = P @ V' + cpb   (M flattened 8192; V' batch = row block >> 11)
  hipLaunchKernelGGL((gemm128<0, true>), dim3(8, 64, 1), blk, 0, stream,
                     Ph, Vt, cpb, out, (_Float16*)nullh, (_Float16*)nullh,
                     (_Float16*)nullh,
                     8192, 1024, 2048, 0L, 2097152L, 0L, 1.0f);
}